// Round 5
// baseline (100.023 us; speedup 1.0000x reference)
//
#include <hip/hip_runtime.h>

constexpr int B = 8;
constexpr int A = 49104;
constexpr int C = 90;
constexpr int M = 32;
constexpr float EPS_CLIP = 1e-4f;
constexpr float LN2 = 0.6931471805599453f;

constexpr int TPB = 256;
constexpr int N4_IMG = A * C / 4;                   // 1,104,840 float4 per image
constexpr int CH4 = 512;                            // float4 per chunk = 8 KB
constexpr int NCHUNKS = (N4_IMG + CH4 - 1) / CH4;   // 2158 (last chunk partial: 456)
constexpr int GX = 256;                             // stream blocks per image (2048 total)

#define GLOBAL_AS __attribute__((address_space(1)))
#define LDS_AS    __attribute__((address_space(3)))

// accum (d_ws): [0..B) S (sum p^2*log2(1-p) over ALL elems), [B..2B) corr (natural),
//               [2B..3B) reg_sum, [3B..4B) pos_cnt

__device__ __forceinline__ float clampp(float v) {
    return fminf(fmaxf(v, EPS_CLIP), 1.f - EPS_CLIP);   // -> v_med3_f32
}

// ---------------- Kernel A: per-anchor assignment, reg loss, corrections ----------------
__global__ __launch_bounds__(TPB) void focal_anchor_kernel(
    const float* __restrict__ cls,   // [B, A, C]
    const float* __restrict__ reg,   // [B, A, 4]
    const float* __restrict__ anc,   // [A, 4]
    const float* __restrict__ ann,   // [B, M, 5]
    float* __restrict__ accum)
{
    __shared__ float s_ann[M * 5];
    __shared__ float s_red[3][TPB / 64];

    const int b = blockIdx.y;
    const int abase = blockIdx.x * TPB;
    const int t = threadIdx.x;

    if (t < M * 5) s_ann[t] = ann[b * M * 5 + t];
    __syncthreads();

    float corr = 0.f, reg_sum = 0.f, pos_cnt = 0.f;
    const int a = abase + t;
    if (a < A) {
        const float4 ab = reinterpret_cast<const float4*>(anc)[a];
        const float aw = ab.z - ab.x;
        const float ah = ab.w - ab.y;
        const float areaA = aw * ah;

        float best = -INFINITY;
        int argm = 0;
        for (int m = 0; m < M; ++m) {
            const float bx1 = s_ann[m * 5 + 0];
            const float by1 = s_ann[m * 5 + 1];
            const float bx2 = s_ann[m * 5 + 2];
            const float by2 = s_ann[m * 5 + 3];
            const float lab = s_ann[m * 5 + 4];
            float iw = fminf(ab.z, bx2) - fmaxf(ab.x, bx1);
            float ih = fminf(ab.w, by2) - fmaxf(ab.y, by1);
            iw = fmaxf(iw, 0.f);
            ih = fmaxf(ih, 0.f);
            const float inter = iw * ih;
            const float ua = fmaxf(areaA + (bx2 - bx1) * (by2 - by1) - inter, 1e-8f);
            const float iou = inter / ua;
            const float val = (lab != -1.0f) ? iou : -1.0f;
            if (val > best) { best = val; argm = m; }    // strict > == first argmax
        }

        if (best >= 0.5f) {
            // ---- positive anchor ----
            pos_cnt = 1.f;
            const float gx1 = s_ann[argm * 5 + 0];
            const float gy1 = s_ann[argm * 5 + 1];
            const float gx2 = s_ann[argm * 5 + 2];
            const float gy2 = s_ann[argm * 5 + 3];
            const float acx = ab.x + 0.5f * aw;
            const float acy = ab.y + 0.5f * ah;
            const float gw0 = gx2 - gx1;
            const float gh0 = gy2 - gy1;
            const float gcx = gx1 + 0.5f * gw0;
            const float gcy = gy1 + 0.5f * gh0;
            const float gw = fmaxf(gw0, 1.f);
            const float gh = fmaxf(gh0, 1.f);
            const float4 rp = reinterpret_cast<const float4*>(reg)[(size_t)b * A + a];
            const float rt0 = (gcx - acx) / aw * 10.f;
            const float rt1 = (gcy - acy) / ah * 10.f;
            const float rt2 = __logf(gw / aw) * 5.f;
            const float rt3 = __logf(gh / ah) * 5.f;
            const float d0 = fabsf(rt0 - rp.x);
            const float d1 = fabsf(rt1 - rp.y);
            const float d2 = fabsf(rt2 - rp.z);
            const float d3 = fabsf(rt3 - rp.w);
            auto sl1 = [](float d) {
                return (d <= (1.f / 9.f)) ? 4.5f * d * d : d - (0.5f / 9.f);
            };
            reg_sum = sl1(d0) + sl1(d1) + sl1(d2) + sl1(d3);

            // correction at the target class: remove streamed neg term, add pos term
            const int cidx = (int)s_ann[argm * 5 + 4];
            const float p = clampp(cls[((size_t)b * A + a) * C + cidx]);
            corr = 0.75f * LN2 * (p * p * __log2f(1.f - p))
                 + 0.25f * (1.f - p) * (1.f - p) * (-__logf(p));
        } else if (best >= 0.4f) {
            // ---- ignore anchor: cancel all 90 streamed neg terms ----
            const float* row = cls + ((size_t)b * A + a) * C;
            float s = 0.f;
            for (int c = 0; c < C; ++c) {
                const float p = clampp(row[c]);
                s = fmaf(p * p, __log2f(1.f - p), s);
            }
            corr = 0.75f * LN2 * s;
        }
    }

    float v0 = corr, v1 = reg_sum, v2 = pos_cnt;
    for (int off = 32; off; off >>= 1) {
        v0 += __shfl_down(v0, off);
        v1 += __shfl_down(v1, off);
        v2 += __shfl_down(v2, off);
    }
    const int wave = t >> 6;
    if ((t & 63) == 0) { s_red[0][wave] = v0; s_red[1][wave] = v1; s_red[2][wave] = v2; }
    __syncthreads();
    if (t == 0) {
        float a0 = 0.f, a1 = 0.f, a2 = 0.f;
        for (int w = 0; w < TPB / 64; ++w) { a0 += s_red[0][w]; a1 += s_red[1][w]; a2 += s_red[2][w]; }
        atomicAdd(&accum[B + b],     a0);
        atomicAdd(&accum[2 * B + b], a1);
        atomicAdd(&accum[3 * B + b], a2);
    }
}

// ------------- Kernel S: LDS-DMA double-buffered streaming reduction -------------
// Per-wave pipeline: each wave stages its own 2KB quarter of an 8KB chunk via
// global_load_lds (no VGPR destination -> compiler cannot re-serialize the loads),
// counted vmcnt keeps the next chunk in flight across the compute phase.
// No __syncthreads in the loop: every wave reads only the LDS region it staged.
__global__ __launch_bounds__(TPB) void focal_stream_kernel(
    const float* __restrict__ cls,   // [B, A, C]
    float* __restrict__ accum)
{
    __shared__ float4 sbuf[2 * CH4];          // 2 x 8KB
    __shared__ float s_red[TPB / 64];

    const int b    = blockIdx.y;
    const int bx   = blockIdx.x;
    const int t    = threadIdx.x;
    const int wid  = t >> 6;                  // wave id (0..3), uniform per wave
    const int lane = t & 63;

    const float4* gimg = reinterpret_cast<const float4*>(cls) + (size_t)b * N4_IMG;
    const int nk = (NCHUNKS - 1 - bx) / GX + 1;   // chunks for this block (8 or 9)

    auto stage = [&](int bufidx, int chunk) {
        // wave 'wid' stages float4 slots [wid*128, wid*128+128) of chunk
        const int slot = wid * 128 + lane;
        int g0 = chunk * CH4 + slot;
        int g1 = g0 + 64;
        g0 = min(g0, N4_IMG - 1);             // clamp: duplicate loads masked in compute
        g1 = min(g1, N4_IMG - 1);
        // LDS dest is wave-uniform base; HW adds lane*16.
        LDS_AS void* l0 = (LDS_AS void*)(sbuf + bufidx * CH4 + wid * 128);
        LDS_AS void* l1 = (LDS_AS void*)(sbuf + bufidx * CH4 + wid * 128 + 64);
        __builtin_amdgcn_global_load_lds((const GLOBAL_AS void*)(gimg + g0), l0, 16, 0, 0);
        __builtin_amdgcn_global_load_lds((const GLOBAL_AS void*)(gimg + g1), l1, 16, 0, 0);
    };

    float acc = 0.f;
    stage(0, bx);
    for (int k = 0; k < nk; ++k) {
        const int c = bx + k * GX;
        // prev iteration's ds_reads fully retired before their buffer is re-staged
        asm volatile("s_waitcnt lgkmcnt(0)" ::: "memory");
        if (k + 1 < nk) {
            stage((k + 1) & 1, c + GX);
            asm volatile("s_waitcnt vmcnt(2)" ::: "memory");  // current chunk's DMA done
        } else {
            asm volatile("s_waitcnt vmcnt(0)" ::: "memory");
        }
        __builtin_amdgcn_sched_barrier(0);

        const float4* buf = sbuf + (k & 1) * CH4;
        const float4 va = buf[2 * t];          // own-wave region: 2t in [wid*128, wid*128+128)
        const float4 vb = buf[2 * t + 1];
        const int i0 = c * CH4 + 2 * t;

        float sa = 0.f, sb = 0.f;
        {
            const float vv[4] = {va.x, va.y, va.z, va.w};
#pragma unroll
            for (int j = 0; j < 4; ++j) {
                const float p = clampp(vv[j]);
                sa = fmaf(p * p, __log2f(1.f - p), sa);
            }
        }
        {
            const float vv[4] = {vb.x, vb.y, vb.z, vb.w};
#pragma unroll
            for (int j = 0; j < 4; ++j) {
                const float p = clampp(vv[j]);
                sb = fmaf(p * p, __log2f(1.f - p), sb);
            }
        }
        if (i0     < N4_IMG) acc += sa;
        if (i0 + 1 < N4_IMG) acc += sb;
    }

    for (int off = 32; off; off >>= 1) acc += __shfl_down(acc, off);
    if ((t & 63) == 0) s_red[t >> 6] = acc;
    __syncthreads();
    if (t == 0) {
        float a0 = 0.f;
        for (int w = 0; w < TPB / 64; ++w) a0 += s_red[w];
        atomicAdd(&accum[b], a0);
    }
}

// ---------------- Finalize ----------------
__global__ void focal_finalize_kernel(const float* __restrict__ ann,
                                      const float* __restrict__ accum,
                                      float* __restrict__ out)
{
    const int t = threadIdx.x;
    float cls_l = 0.f, reg_l = 0.f;
    if (t < B) {
        bool has = false;
        for (int m = 0; m < M; ++m)
            has = has || (ann[t * M * 5 + m * 5 + 4] != -1.0f);
        const float S    = accum[t];
        const float corr = accum[B + t];
        const float rs   = accum[2 * B + t];
        const float np   = accum[3 * B + t];
        const float cls_sum = -0.75f * LN2 * S + corr;
        cls_l = has ? cls_sum / fmaxf(np, 1.f) : 0.f;
        reg_l = (has && np > 0.f) ? rs / fmaxf(np * 4.f, 1.f) : 0.f;
    }
    for (int off = 4; off; off >>= 1) {
        cls_l += __shfl_down(cls_l, off);
        reg_l += __shfl_down(reg_l, off);
    }
    if (t == 0) {
        out[0] = cls_l * (1.f / B);
        out[1] = reg_l * (1.f / B);
    }
}

extern "C" void kernel_launch(void* const* d_in, const int* in_sizes, int n_in,
                              void* d_out, int out_size, void* d_ws, size_t ws_size,
                              hipStream_t stream) {
    const float* cls = (const float*)d_in[0];
    const float* reg = (const float*)d_in[1];
    const float* anc = (const float*)d_in[2];
    const float* ann = (const float*)d_in[3];
    float* out = (float*)d_out;
    float* accum = (float*)d_ws;

    hipMemsetAsync(accum, 0, 4 * B * sizeof(float), stream);

    dim3 gridA((A + TPB - 1) / TPB, B);
    focal_anchor_kernel<<<gridA, TPB, 0, stream>>>(cls, reg, anc, ann, accum);

    dim3 gridS(GX, B);
    focal_stream_kernel<<<gridS, TPB, 0, stream>>>(cls, accum);

    focal_finalize_kernel<<<1, 64, 0, stream>>>(ann, accum, out);
}

// Round 6
// 98.954 us; speedup vs baseline: 1.0108x; 1.0108x over previous
//
#include <hip/hip_runtime.h>

constexpr int B = 8;
constexpr int A = 49104;
constexpr int C = 90;
constexpr int M = 32;
constexpr float EPS_CLIP = 1e-4f;
constexpr float LN2 = 0.6931471805599453f;

constexpr int TPB = 256;
constexpr int N4_IMG = A * C / 4;                   // 1,104,840 float4 per image
constexpr int CH4 = 512;                            // float4 per chunk = 8 KB
constexpr int NCHUNKS = (N4_IMG + CH4 - 1) / CH4;   // 2158 (last partial: 456)
constexpr int GX = 256;                             // stream blocks per image

#define GLOBAL_AS __attribute__((address_space(1)))
#define LDS_AS    __attribute__((address_space(3)))

// accum (d_ws): [0..B) S (sum p^2*log2(1-p) over ALL elems), [B..2B) corr (natural),
//               [2B..3B) reg_sum, [3B..4B) pos_cnt

__device__ __forceinline__ float clampp(float v) {
    return fminf(fmaxf(v, EPS_CLIP), 1.f - EPS_CLIP);   // -> v_med3_f32
}

// ---------------- Kernel A: assignment + reg loss + corrections (coop rows) ----------------
__global__ __launch_bounds__(TPB) void focal_anchor_kernel(
    const float* __restrict__ cls,   // [B, A, C]
    const float* __restrict__ reg,   // [B, A, 4]
    const float* __restrict__ anc,   // [A, 4]
    const float* __restrict__ ann,   // [B, M, 5]
    float* __restrict__ accum)
{
    __shared__ float s_ann[M * 5];
    __shared__ float s_red[3][TPB / 64];
    __shared__ int   s_list[TPB];        // block-local ignore-anchor worklist
    __shared__ int   s_cnt;

    const int b = blockIdx.y;
    const int abase = blockIdx.x * TPB;
    const int t = threadIdx.x;
    const int wid  = t >> 6;
    const int lane = t & 63;

    if (t < M * 5) s_ann[t] = ann[b * M * 5 + t];
    if (t == 0) s_cnt = 0;
    __syncthreads();

    float corr = 0.f, reg_sum = 0.f, pos_cnt = 0.f;
    const int a = abase + t;
    if (a < A) {
        const float4 ab = reinterpret_cast<const float4*>(anc)[a];
        const float aw = ab.z - ab.x;
        const float ah = ab.w - ab.y;
        const float areaA = aw * ah;

        float best = -INFINITY;
        int argm = 0;
        for (int m = 0; m < M; ++m) {
            const float bx1 = s_ann[m * 5 + 0];
            const float by1 = s_ann[m * 5 + 1];
            const float bx2 = s_ann[m * 5 + 2];
            const float by2 = s_ann[m * 5 + 3];
            const float lab = s_ann[m * 5 + 4];
            float iw = fminf(ab.z, bx2) - fmaxf(ab.x, bx1);
            float ih = fminf(ab.w, by2) - fmaxf(ab.y, by1);
            iw = fmaxf(iw, 0.f);
            ih = fmaxf(ih, 0.f);
            const float inter = iw * ih;
            const float ua = fmaxf(areaA + (bx2 - bx1) * (by2 - by1) - inter, 1e-8f);
            const float iou = inter / ua;
            const float val = (lab != -1.0f) ? iou : -1.0f;
            if (val > best) { best = val; argm = m; }    // strict > == first argmax
        }

        if (best >= 0.5f) {
            // ---- positive anchor: reg loss + single-class correction ----
            pos_cnt = 1.f;
            const float gx1 = s_ann[argm * 5 + 0];
            const float gy1 = s_ann[argm * 5 + 1];
            const float gx2 = s_ann[argm * 5 + 2];
            const float gy2 = s_ann[argm * 5 + 3];
            const float acx = ab.x + 0.5f * aw;
            const float acy = ab.y + 0.5f * ah;
            const float gw0 = gx2 - gx1;
            const float gh0 = gy2 - gy1;
            const float gcx = gx1 + 0.5f * gw0;
            const float gcy = gy1 + 0.5f * gh0;
            const float gw = fmaxf(gw0, 1.f);
            const float gh = fmaxf(gh0, 1.f);
            const float4 rp = reinterpret_cast<const float4*>(reg)[(size_t)b * A + a];
            const float rt0 = (gcx - acx) / aw * 10.f;
            const float rt1 = (gcy - acy) / ah * 10.f;
            const float rt2 = __logf(gw / aw) * 5.f;
            const float rt3 = __logf(gh / ah) * 5.f;
            const float d0 = fabsf(rt0 - rp.x);
            const float d1 = fabsf(rt1 - rp.y);
            const float d2 = fabsf(rt2 - rp.z);
            const float d3 = fabsf(rt3 - rp.w);
            auto sl1 = [](float d) {
                return (d <= (1.f / 9.f)) ? 4.5f * d * d : d - (0.5f / 9.f);
            };
            reg_sum = sl1(d0) + sl1(d1) + sl1(d2) + sl1(d3);

            const int cidx = (int)s_ann[argm * 5 + 4];
            const float p = clampp(cls[((size_t)b * A + a) * C + cidx]);
            corr = 0.75f * LN2 * (p * p * __log2f(1.f - p))      // cancel streamed neg term
                 + 0.25f * (1.f - p) * (1.f - p) * (-__logf(p)); // true positive term
        } else if (best >= 0.4f) {
            // ---- ignore anchor: defer full-row cancellation to phase 2 ----
            const int slot = atomicAdd(&s_cnt, 1);
            s_list[slot] = t;
        }
    }
    __syncthreads();

    // ---- Phase 2: wave-cooperative coalesced row sums for ignore anchors ----
    const int cnt = s_cnt;
    for (int i = wid; i < cnt; i += TPB / 64) {
        const int aidx = s_list[i];                      // uniform per wave (LDS broadcast)
        const float* row = cls + ((size_t)b * A + abase + aidx) * (size_t)C;
        float s = 0.f;
        if (lane < C) {                                  // lanes 0..63
            const float p = clampp(row[lane]);
            s = p * p * __log2f(1.f - p);
        }
        if (lane + 64 < C) {                             // lanes 0..25
            const float p = clampp(row[lane + 64]);
            s = fmaf(p * p, __log2f(1.f - p), s);
        }
        for (int off = 32; off; off >>= 1) s += __shfl_down(s, off);
        if (lane == 0) corr += 0.75f * LN2 * s;          // cancels the 90 streamed terms
    }

    // ---- block reduce {corr, reg_sum, pos_cnt} ----
    float v0 = corr, v1 = reg_sum, v2 = pos_cnt;
    for (int off = 32; off; off >>= 1) {
        v0 += __shfl_down(v0, off);
        v1 += __shfl_down(v1, off);
        v2 += __shfl_down(v2, off);
    }
    if (lane == 0) { s_red[0][wid] = v0; s_red[1][wid] = v1; s_red[2][wid] = v2; }
    __syncthreads();
    if (t == 0) {
        float a0 = 0.f, a1 = 0.f, a2 = 0.f;
        for (int w = 0; w < TPB / 64; ++w) { a0 += s_red[0][w]; a1 += s_red[1][w]; a2 += s_red[2][w]; }
        atomicAdd(&accum[B + b],     a0);
        atomicAdd(&accum[2 * B + b], a1);
        atomicAdd(&accum[3 * B + b], a2);
    }
}

// ------------- Kernel S: LDS-DMA double-buffered streaming reduction (unchanged) -------------
__global__ __launch_bounds__(TPB) void focal_stream_kernel(
    const float* __restrict__ cls,   // [B, A, C]
    float* __restrict__ accum)
{
    __shared__ float4 sbuf[2 * CH4];          // 2 x 8KB
    __shared__ float s_red[TPB / 64];

    const int b    = blockIdx.y;
    const int bx   = blockIdx.x;
    const int t    = threadIdx.x;
    const int wid  = t >> 6;
    const int lane = t & 63;

    const float4* gimg = reinterpret_cast<const float4*>(cls) + (size_t)b * N4_IMG;
    const int nk = (NCHUNKS - 1 - bx) / GX + 1;

    auto stage = [&](int bufidx, int chunk) {
        const int slot = wid * 128 + lane;
        int g0 = chunk * CH4 + slot;
        int g1 = g0 + 64;
        g0 = min(g0, N4_IMG - 1);
        g1 = min(g1, N4_IMG - 1);
        LDS_AS void* l0 = (LDS_AS void*)(sbuf + bufidx * CH4 + wid * 128);
        LDS_AS void* l1 = (LDS_AS void*)(sbuf + bufidx * CH4 + wid * 128 + 64);
        __builtin_amdgcn_global_load_lds((const GLOBAL_AS void*)(gimg + g0), l0, 16, 0, 0);
        __builtin_amdgcn_global_load_lds((const GLOBAL_AS void*)(gimg + g1), l1, 16, 0, 0);
    };

    float acc = 0.f;
    stage(0, bx);
    for (int k = 0; k < nk; ++k) {
        const int c = bx + k * GX;
        asm volatile("s_waitcnt lgkmcnt(0)" ::: "memory");
        if (k + 1 < nk) {
            stage((k + 1) & 1, c + GX);
            asm volatile("s_waitcnt vmcnt(2)" ::: "memory");
        } else {
            asm volatile("s_waitcnt vmcnt(0)" ::: "memory");
        }
        __builtin_amdgcn_sched_barrier(0);

        const float4* buf = sbuf + (k & 1) * CH4;
        const float4 va = buf[2 * t];
        const float4 vb = buf[2 * t + 1];
        const int i0 = c * CH4 + 2 * t;

        float sa = 0.f, sb = 0.f;
        {
            const float vv[4] = {va.x, va.y, va.z, va.w};
#pragma unroll
            for (int j = 0; j < 4; ++j) {
                const float p = clampp(vv[j]);
                sa = fmaf(p * p, __log2f(1.f - p), sa);
            }
        }
        {
            const float vv[4] = {vb.x, vb.y, vb.z, vb.w};
#pragma unroll
            for (int j = 0; j < 4; ++j) {
                const float p = clampp(vv[j]);
                sb = fmaf(p * p, __log2f(1.f - p), sb);
            }
        }
        if (i0     < N4_IMG) acc += sa;
        if (i0 + 1 < N4_IMG) acc += sb;
    }

    for (int off = 32; off; off >>= 1) acc += __shfl_down(acc, off);
    if ((t & 63) == 0) s_red[t >> 6] = acc;
    __syncthreads();
    if (t == 0) {
        float a0 = 0.f;
        for (int w = 0; w < TPB / 64; ++w) a0 += s_red[w];
        atomicAdd(&accum[b], a0);
    }
}

// ---------------- Finalize ----------------
__global__ void focal_finalize_kernel(const float* __restrict__ ann,
                                      const float* __restrict__ accum,
                                      float* __restrict__ out)
{
    const int t = threadIdx.x;
    float cls_l = 0.f, reg_l = 0.f;
    if (t < B) {
        bool has = false;
        for (int m = 0; m < M; ++m)
            has = has || (ann[t * M * 5 + m * 5 + 4] != -1.0f);
        const float S    = accum[t];
        const float corr = accum[B + t];
        const float rs   = accum[2 * B + t];
        const float np   = accum[3 * B + t];
        const float cls_sum = -0.75f * LN2 * S + corr;
        cls_l = has ? cls_sum / fmaxf(np, 1.f) : 0.f;
        reg_l = (has && np > 0.f) ? rs / fmaxf(np * 4.f, 1.f) : 0.f;
    }
    for (int off = 4; off; off >>= 1) {
        cls_l += __shfl_down(cls_l, off);
        reg_l += __shfl_down(reg_l, off);
    }
    if (t == 0) {
        out[0] = cls_l * (1.f / B);
        out[1] = reg_l * (1.f / B);
    }
}

extern "C" void kernel_launch(void* const* d_in, const int* in_sizes, int n_in,
                              void* d_out, int out_size, void* d_ws, size_t ws_size,
                              hipStream_t stream) {
    const float* cls = (const float*)d_in[0];
    const float* reg = (const float*)d_in[1];
    const float* anc = (const float*)d_in[2];
    const float* ann = (const float*)d_in[3];
    float* out = (float*)d_out;
    float* accum = (float*)d_ws;

    hipMemsetAsync(accum, 0, 4 * B * sizeof(float), stream);

    // S first: streams cls through L3 so A's scattered row reads hit cache.
    dim3 gridS(GX, B);
    focal_stream_kernel<<<gridS, TPB, 0, stream>>>(cls, accum);

    dim3 gridA((A + TPB - 1) / TPB, B);
    focal_anchor_kernel<<<gridA, TPB, 0, stream>>>(cls, reg, anc, ann, accum);

    focal_finalize_kernel<<<1, 64, 0, stream>>>(ann, accum, out);
}

// Round 8
// 72.373 us; speedup vs baseline: 1.3821x; 1.3673x over previous
//
#include <hip/hip_runtime.h>

constexpr int B = 8;
constexpr int A = 49104;
constexpr int C = 90;
constexpr int M = 32;
constexpr float EPS_CLIP = 1e-4f;
constexpr float LN2 = 0.6931471805599453f;

constexpr int TPB = 256;
constexpr int N4_TOT = B * A * C / 4;               // 8,838,720 float4 total
constexpr int N4_IMG = A * C / 4;                   // 1,104,840 float4 per image
constexpr int SL4 = 4096;                           // float4 per block slice (64 KB)
constexpr int NBLK = (N4_TOT + SL4 - 1) / SL4;      // 2158 (last slice = 3648)
constexpr int ABPI = (A + TPB - 1) / TPB;           // 192 anchor-blocks per image
constexpr int NABLK = ABPI * B;                     // 1536

typedef float f32x4 __attribute__((ext_vector_type(4)));  // NT-load-compatible

// accum (d_ws): [0..B) S (sum p^2*log2(1-p), log2 domain), [B..2B) corr (natural),
//               [2B..3B) reg_sum, [3B..4B) pos_cnt

__device__ __forceinline__ float clampp(float v) {
    return fminf(fmaxf(v, EPS_CLIP), 1.f - EPS_CLIP);
}

__device__ __forceinline__ float neg4(f32x4 v) {
    float s = 0.f;
#pragma unroll
    for (int j = 0; j < 4; ++j) {
        const float p = clampp(v[j]);
        s = fmaf(p * p, __log2f(1.f - p), s);
    }
    return s;
}

__global__ __launch_bounds__(TPB) void focal_main_kernel(
    const float* __restrict__ cls,   // [B, A, C]
    const float* __restrict__ reg,   // [B, A, 4]
    const float* __restrict__ anc,   // [A, 4]
    const float* __restrict__ ann,   // [B, M, 5]
    float* __restrict__ accum)
{
    __shared__ float s_ann[M * 5];
    __shared__ float s_red[3][TPB / 64];
    __shared__ int   s_list[TPB];
    __shared__ int   s_cnt;

    const int t    = threadIdx.x;
    const int wid  = t >> 6;
    const int lane = t & 63;
    const int blk  = blockIdx.x;

    // ================= Anchor phase (blocks 0..NABLK-1 only) =================
    if (blk < NABLK) {
        const int b     = blk / ABPI;
        const int abase = (blk - b * ABPI) * TPB;

        if (t < M * 5) s_ann[t] = ann[b * M * 5 + t];
        if (t == 0) s_cnt = 0;
        __syncthreads();

        float corr = 0.f, reg_sum = 0.f, pos_cnt = 0.f;
        const int a = abase + t;
        if (a < A) {
            const float4 ab = reinterpret_cast<const float4*>(anc)[a];
            const float aw = ab.z - ab.x;
            const float ah = ab.w - ab.y;
            const float areaA = aw * ah;

            float best = -INFINITY;
            int argm = 0;
            for (int m = 0; m < M; ++m) {
                const float bx1 = s_ann[m * 5 + 0];
                const float by1 = s_ann[m * 5 + 1];
                const float bx2 = s_ann[m * 5 + 2];
                const float by2 = s_ann[m * 5 + 3];
                const float lab = s_ann[m * 5 + 4];
                float iw = fminf(ab.z, bx2) - fmaxf(ab.x, bx1);
                float ih = fminf(ab.w, by2) - fmaxf(ab.y, by1);
                iw = fmaxf(iw, 0.f);
                ih = fmaxf(ih, 0.f);
                const float inter = iw * ih;
                const float ua = fmaxf(areaA + (bx2 - bx1) * (by2 - by1) - inter, 1e-8f);
                const float iou = inter / ua;
                const float val = (lab != -1.0f) ? iou : -1.0f;
                if (val > best) { best = val; argm = m; }   // strict > == first argmax
            }

            if (best >= 0.5f) {
                pos_cnt = 1.f;
                const float gx1 = s_ann[argm * 5 + 0];
                const float gy1 = s_ann[argm * 5 + 1];
                const float gx2 = s_ann[argm * 5 + 2];
                const float gy2 = s_ann[argm * 5 + 3];
                const float acx = ab.x + 0.5f * aw;
                const float acy = ab.y + 0.5f * ah;
                const float gw0 = gx2 - gx1;
                const float gh0 = gy2 - gy1;
                const float gcx = gx1 + 0.5f * gw0;
                const float gcy = gy1 + 0.5f * gh0;
                const float gw = fmaxf(gw0, 1.f);
                const float gh = fmaxf(gh0, 1.f);
                const float4 rp = reinterpret_cast<const float4*>(reg)[(size_t)b * A + a];
                const float rt0 = (gcx - acx) / aw * 10.f;
                const float rt1 = (gcy - acy) / ah * 10.f;
                const float rt2 = __logf(gw / aw) * 5.f;
                const float rt3 = __logf(gh / ah) * 5.f;
                const float d0 = fabsf(rt0 - rp.x);
                const float d1 = fabsf(rt1 - rp.y);
                const float d2 = fabsf(rt2 - rp.z);
                const float d3 = fabsf(rt3 - rp.w);
                auto sl1 = [](float d) {
                    return (d <= (1.f / 9.f)) ? 4.5f * d * d : d - (0.5f / 9.f);
                };
                reg_sum = sl1(d0) + sl1(d1) + sl1(d2) + sl1(d3);

                const int cidx = (int)s_ann[argm * 5 + 4];
                const float p = clampp(cls[((size_t)b * A + a) * C + cidx]);
                corr = 0.75f * LN2 * (p * p * __log2f(1.f - p))      // cancel streamed term
                     + 0.25f * (1.f - p) * (1.f - p) * (-__logf(p)); // true positive term
            } else if (best >= 0.4f) {
                const int slot = atomicAdd(&s_cnt, 1);
                s_list[slot] = t;
            }
        }
        __syncthreads();

        // wave-cooperative coalesced row sums for ignore anchors
        const int cnt = s_cnt;
        for (int i = wid; i < cnt; i += TPB / 64) {
            const int aidx = s_list[i];
            const float* row = cls + ((size_t)b * A + abase + aidx) * (size_t)C;
            float s = 0.f;
            if (lane < C) {
                const float p = clampp(row[lane]);
                s = p * p * __log2f(1.f - p);
            }
            if (lane + 64 < C) {
                const float p = clampp(row[lane + 64]);
                s = fmaf(p * p, __log2f(1.f - p), s);
            }
            for (int off = 32; off; off >>= 1) s += __shfl_down(s, off);
            if (lane == 0) corr += 0.75f * LN2 * s;
        }

        float v0 = corr, v1 = reg_sum, v2 = pos_cnt;
        for (int off = 32; off; off >>= 1) {
            v0 += __shfl_down(v0, off);
            v1 += __shfl_down(v1, off);
            v2 += __shfl_down(v2, off);
        }
        if (lane == 0) { s_red[0][wid] = v0; s_red[1][wid] = v1; s_red[2][wid] = v2; }
        __syncthreads();
        if (t == 0) {
            float a0 = 0.f, a1 = 0.f, a2 = 0.f;
            for (int w = 0; w < TPB / 64; ++w) {
                a0 += s_red[0][w]; a1 += s_red[1][w]; a2 += s_red[2][w];
            }
            atomicAdd(&accum[B + b],     a0);
            atomicAdd(&accum[2 * B + b], a1);
            atomicAdd(&accum[3 * B + b], a2);
        }
        __syncthreads();   // s_red reused below
    }

    // ================= Stream phase (ALL blocks, uniform) =================
    const f32x4* __restrict__ cls4 = reinterpret_cast<const f32x4*>(cls);
    const int sbase = blk * SL4;
    const int nsl   = min(SL4, N4_TOT - sbase);
    const int img0  = sbase / N4_IMG;
    const int imgL  = (sbase + nsl - 1) / N4_IMG;

    float acc0 = 0.f, acc1 = 0.f;
    if (img0 == imgL) {
        // clean block: contiguous slice within one image; 8-deep unrolled batches
        const f32x4* p = cls4 + sbase + t;
        int i = t;
        for (; i + 7 * TPB < nsl; i += 8 * TPB) {
            f32x4 v[8];
#pragma unroll
            for (int k = 0; k < 8; ++k)
                v[k] = __builtin_nontemporal_load(&p[k * TPB]);
            p += 8 * TPB;
#pragma unroll
            for (int k = 0; k < 8; ++k) acc0 += neg4(v[k]);
        }
        for (; i < nsl; i += TPB) {
            acc0 += neg4(__builtin_nontemporal_load(p));
            p += TPB;
        }
    } else {
        // image-boundary block (7 of 2158): per-element image split
        const int split = (img0 + 1) * N4_IMG;
        for (int i = t; i < nsl; i += TPB) {
            const float s = neg4(__builtin_nontemporal_load(&cls4[sbase + i]));
            if (sbase + i < split) acc0 += s; else acc1 += s;
        }
    }

    float w0 = acc0, w1 = acc1;
    for (int off = 32; off; off >>= 1) {
        w0 += __shfl_down(w0, off);
        w1 += __shfl_down(w1, off);
    }
    if (lane == 0) { s_red[0][wid] = w0; s_red[1][wid] = w1; }
    __syncthreads();
    if (t == 0) {
        float a0 = 0.f, a1 = 0.f;
        for (int w = 0; w < TPB / 64; ++w) { a0 += s_red[0][w]; a1 += s_red[1][w]; }
        atomicAdd(&accum[img0], a0);
        if (imgL != img0) atomicAdd(&accum[imgL], a1);
    }
}

// ---------------- Finalize ----------------
__global__ void focal_finalize_kernel(const float* __restrict__ ann,
                                      const float* __restrict__ accum,
                                      float* __restrict__ out)
{
    const int t = threadIdx.x;
    float cls_l = 0.f, reg_l = 0.f;
    if (t < B) {
        bool has = false;
        for (int m = 0; m < M; ++m)
            has = has || (ann[t * M * 5 + m * 5 + 4] != -1.0f);
        const float S    = accum[t];
        const float corr = accum[B + t];
        const float rs   = accum[2 * B + t];
        const float np   = accum[3 * B + t];
        const float cls_sum = -0.75f * LN2 * S + corr;
        cls_l = has ? cls_sum / fmaxf(np, 1.f) : 0.f;
        reg_l = (has && np > 0.f) ? rs / fmaxf(np * 4.f, 1.f) : 0.f;
    }
    for (int off = 4; off; off >>= 1) {
        cls_l += __shfl_down(cls_l, off);
        reg_l += __shfl_down(reg_l, off);
    }
    if (t == 0) {
        out[0] = cls_l * (1.f / B);
        out[1] = reg_l * (1.f / B);
    }
}

extern "C" void kernel_launch(void* const* d_in, const int* in_sizes, int n_in,
                              void* d_out, int out_size, void* d_ws, size_t ws_size,
                              hipStream_t stream) {
    const float* cls = (const float*)d_in[0];
    const float* reg = (const float*)d_in[1];
    const float* anc = (const float*)d_in[2];
    const float* ann = (const float*)d_in[3];
    float* out = (float*)d_out;
    float* accum = (float*)d_ws;

    (void)hipMemsetAsync(accum, 0, 4 * B * sizeof(float), stream);

    focal_main_kernel<<<dim3(NBLK), TPB, 0, stream>>>(cls, reg, anc, ann, accum);
    focal_finalize_kernel<<<1, 64, 0, stream>>>(ann, accum, out);
}